// Round 1
// baseline (136.036 us; speedup 1.0000x reference)
//
#include <hip/hip_runtime.h>
#include <math.h>

#define NATOMS 4096
#define FDIM   256
#define NHEAD  8
#define DHEAD  32
#define NGRP   128

typedef __bf16 bf16x8 __attribute__((ext_vector_type(8)));
typedef float  floatx4 __attribute__((ext_vector_type(4)));
typedef unsigned short u16x4 __attribute__((ext_vector_type(4)));

__device__ __forceinline__ float silu_f(float x) {
    return x / (1.0f + __expf(-x));
}

__device__ __forceinline__ unsigned short f2bf(float f) {
    union { float f; unsigned int u; } a;
    a.f = f;
    unsigned int r = a.u + 0x7FFF + ((a.u >> 16) & 1);   // RNE
    return (unsigned short)(r >> 16);
}

// ---------------------------------------------------------------------------
// Prep: convert x -> xb (bf16), Wq|Wk|Wv -> Wb (bf16, [768,256]),
// concat biases -> b_all[768]; block 0 also computes group offsets.
// Unit = one float4. x: 262144 units, each W: 16384 units. Grid = 1216 x 256.
// ---------------------------------------------------------------------------
__global__ __launch_bounds__(256) void prep_kernel(
    const float* __restrict__ x,
    const float* __restrict__ Wq, const float* __restrict__ Wk, const float* __restrict__ Wv,
    const float* __restrict__ bq, const float* __restrict__ bk, const float* __restrict__ bv,
    const int* __restrict__ seg,
    unsigned short* __restrict__ xb, unsigned short* __restrict__ Wb,
    float* __restrict__ b_all, int* __restrict__ off)
{
    int tid = threadIdx.x;
    unsigned int u = blockIdx.x * 256 + tid;

    if (blockIdx.x == 0 && tid < NGRP) {
        int g = tid;
        auto lb = [&](int val) {
            int lo = 0, hi = NATOMS;
            while (lo < hi) {
                int mid = (lo + hi) >> 1;
                if (seg[mid] < val) lo = mid + 1; else hi = mid;
            }
            return lo;
        };
        int a = lb(g);
        off[g] = a;
        if (g == NGRP - 1) off[NGRP] = NATOMS;
    }
    if (blockIdx.x == 1 && tid < 192) {
        // bias concat as float4: 64 per projection
        const float* src = (tid < 64) ? bq : (tid < 128) ? bk : bv;
        int t = tid & 63;
        ((float4*)b_all)[tid] = ((const float4*)src)[t];
    }

    const unsigned int NX4 = 262144;   // x float4 count
    const unsigned int NW4 = 16384;    // per-W float4 count
    float4 fv;
    u16x4* dst;
    if (u < NX4) {
        fv = ((const float4*)x)[u];
        dst = (u16x4*)xb + u;
    } else {
        unsigned int r = u - NX4;
        unsigned int w = r / NW4;       // 0..2
        unsigned int i = r - w * NW4;
        const float* W = (w == 0) ? Wq : (w == 1) ? Wk : Wv;
        fv = ((const float4*)W)[i];
        dst = (u16x4*)Wb + (size_t)w * NW4 + i;
    }
    u16x4 o;
    o[0] = f2bf(fv.x); o[1] = f2bf(fv.y); o[2] = f2bf(fv.z); o[3] = f2bf(fv.w);
    *dst = o;
}

// ---------------------------------------------------------------------------
// QKV projection via MFMA: D[4096,768] = xb @ Wb^T + b_all, scattered into
// contiguous fp32 q|k|v (qkv + (n>>8)*NF + m*256 + (n&255)).
// Block = 256 thr = 4 waves in 2x2; wave tile 32x64 (2 m-frag x 4 n-frag),
// block tile 64x128. No LDS: fragments loaded straight from global (L2-hot).
// Grid: (4096/64, 768/128) = (64, 6).
// ---------------------------------------------------------------------------
__global__ __launch_bounds__(256) void qkv_mfma(
    const unsigned short* __restrict__ xb, const unsigned short* __restrict__ Wb,
    const float* __restrict__ b_all, float* __restrict__ qkv)
{
    int tid = threadIdx.x;
    int lane = tid & 63;
    int ww = tid >> 6;
    int wrow = ww >> 1, wcol = ww & 1;
    int m_base = blockIdx.x * 64 + wrow * 32;
    int n_base = blockIdx.y * 128 + wcol * 64;

    int l15 = lane & 15;
    int quad = lane >> 4;
    int kq = quad * 8;

    floatx4 acc[2][4] = {};

    const unsigned short* arow0 = xb + (size_t)(m_base + l15) * 256 + kq;
    const unsigned short* arow1 = arow0 + 16 * 256;
    const unsigned short* brow[4];
#pragma unroll
    for (int ni = 0; ni < 4; ++ni)
        brow[ni] = Wb + (size_t)(n_base + ni * 16 + l15) * 256 + kq;

#pragma unroll
    for (int ks = 0; ks < 8; ++ks) {
        int ko = ks * 32;
        bf16x8 a0 = *(const bf16x8*)(arow0 + ko);
        bf16x8 a1 = *(const bf16x8*)(arow1 + ko);
#pragma unroll
        for (int ni = 0; ni < 4; ++ni) {
            bf16x8 b = *(const bf16x8*)(brow[ni] + ko);
            acc[0][ni] = __builtin_amdgcn_mfma_f32_16x16x32_bf16(a0, b, acc[0][ni], 0, 0, 0);
            acc[1][ni] = __builtin_amdgcn_mfma_f32_16x16x32_bf16(a1, b, acc[1][ni], 0, 0, 0);
        }
    }

#pragma unroll
    for (int mi = 0; mi < 2; ++mi) {
#pragma unroll
        for (int ni = 0; ni < 4; ++ni) {
            int col_g = n_base + ni * 16 + l15;
            int w = col_g >> 8, c = col_g & 255;
            float bias = b_all[col_g];
            float* outp = qkv + (size_t)w * (NATOMS * FDIM) + c;
#pragma unroll
            for (int r = 0; r < 4; ++r) {
                int row = m_base + mi * 16 + quad * 4 + r;
                outp[(size_t)row * FDIM] = acc[mi][ni][r] + bias;
            }
        }
    }
}

// ---------------------------------------------------------------------------
// Fused: block-diagonal attention row-sum + both output GEMMs + silu.
// One block per group g (256 thr = 8 heads x 32 lanes).
//   Phase A: w_j^h = sum_i silu(q_i^h . k_j^h)   (thread (h, lane=j) owns k_j
//            in regs; q tiles staged in LDS, 32-way reuse per head)
//            ysum[h*32+d] += sum_j w_j^h * v_j^h[d]   (v read once -> global)
//   Phase B: S[t]  = ysum . Wo1[t,:] + n * bo1[t]
//            out[t] = silu(S . Wo2[t,:] + bo2[t])     (row-independent per g)
// ---------------------------------------------------------------------------
#define QT 32

__global__ __launch_bounds__(256) void attn_out(
    const float* __restrict__ q, const float* __restrict__ k,
    const float* __restrict__ v, const int* __restrict__ off,
    const float* __restrict__ Wo1, const float* __restrict__ bo1,
    const float* __restrict__ Wo2, const float* __restrict__ bo2,
    float* __restrict__ out)
{
    int g = blockIdx.x;
    int base = off[g];
    int end  = off[g + 1];
    // clamp against garbage (rocprof replay may run with poisoned workspace)
    base = min(max(base, 0), NATOMS);
    end  = min(max(end, base), NATOMS);
    int n = end - base;

    __shared__ float4 qt4[QT * 64];   // 32 KB: q tile, all heads
    __shared__ float  wloc[256];      // w_j per (h, j-lane)
    __shared__ float  ybuf[FDIM];     // Ysum row
    __shared__ float  sbuf[FDIM];     // S row

    int tid  = threadIdx.x;
    int h    = tid >> 5;
    int lane = tid & 31;

    const float4* q4 = (const float4*)(q + (size_t)base * FDIM);
    const float*  kg = k + (size_t)base * FDIM + h * DHEAD;
    const float*  vg = v + (size_t)base * FDIM + h * DHEAD;

    float ysum = 0.0f;

    for (int j0 = 0; j0 < n; j0 += 32) {
        int jt_n = min(32, n - j0);

        // this thread's k row (clamped for idle lanes)
        int jrow = (lane < jt_n) ? (j0 + lane) : j0;
        float4 kr[8];
        const float4* kp = (const float4*)(kg + (size_t)jrow * FDIM);
#pragma unroll
        for (int c = 0; c < 8; ++c) kr[c] = kp[c];

        float wpart = 0.0f;
        for (int i0 = 0; i0 < n; i0 += QT) {
            int it_n = min(QT, n - i0);
            __syncthreads();
            for (int idx = tid; idx < it_n * 64; idx += 256)
                qt4[idx] = q4[(size_t)(i0 + (idx >> 6)) * 64 + (idx & 63)];
            __syncthreads();
            if (lane < jt_n) {
                const float4* qh = qt4 + h * 8;
                for (int ii = 0; ii < it_n; ++ii) {
                    const float4* qr = qh + ii * 64;
                    float s = 0.0f;
#pragma unroll
                    for (int c = 0; c < 8; ++c) {
                        float4 a = qr[c];
                        s = fmaf(a.x, kr[c].x, s);
                        s = fmaf(a.y, kr[c].y, s);
                        s = fmaf(a.z, kr[c].z, s);
                        s = fmaf(a.w, kr[c].w, s);
                    }
                    wpart += silu_f(s);
                }
            }
        }
        wloc[tid] = wpart;
        __syncthreads();
        // Ysum accumulate: thread role now (h, d=lane); v elements used once
        for (int j = 0; j < jt_n; ++j)
            ysum = fmaf(wloc[h * 32 + j], vg[(size_t)(j0 + j) * FDIM + lane], ysum);
        // wloc rewritten only after next iter's i-loop __syncthreads -> safe
    }

    ybuf[tid] = ysum;
    __syncthreads();

    // ---- Phase B: two 256x256 row-GEMVs, one output column per thread ----
    float cnt = (float)n;
    const float4* y4 = (const float4*)ybuf;
    const float4* w1 = (const float4*)(Wo1 + (size_t)tid * FDIM);
    float acc = cnt * bo1[tid];
#pragma unroll
    for (int c = 0; c < 64; ++c) {
        float4 a = y4[c], b = w1[c];
        acc = fmaf(a.x, b.x, acc);
        acc = fmaf(a.y, b.y, acc);
        acc = fmaf(a.z, b.z, acc);
        acc = fmaf(a.w, b.w, acc);
    }
    sbuf[tid] = acc;
    __syncthreads();

    const float4* s4 = (const float4*)sbuf;
    const float4* w2 = (const float4*)(Wo2 + (size_t)tid * FDIM);
    float acc2 = bo2[tid];
#pragma unroll
    for (int c = 0; c < 64; ++c) {
        float4 a = s4[c], b = w2[c];
        acc2 = fmaf(a.x, b.x, acc2);
        acc2 = fmaf(a.y, b.y, acc2);
        acc2 = fmaf(a.z, b.z, acc2);
        acc2 = fmaf(a.w, b.w, acc2);
    }
    out[(size_t)g * FDIM + tid] = silu_f(acc2);
}

// ---------------------------------------------------------------------------
extern "C" void kernel_launch(void* const* d_in, const int* in_sizes, int n_in,
                              void* d_out, int out_size, void* d_ws, size_t ws_size,
                              hipStream_t stream) {
    const float* x    = (const float*)d_in[0];
    const int*   eidx = (const int*)  d_in[1];
    const float* Wq   = (const float*)d_in[2];
    const float* bq   = (const float*)d_in[3];
    const float* Wk   = (const float*)d_in[4];
    const float* bk   = (const float*)d_in[5];
    const float* Wv   = (const float*)d_in[6];
    const float* bv   = (const float*)d_in[7];
    const float* Wo1  = (const float*)d_in[8];
    const float* bo1  = (const float*)d_in[9];
    const float* Wo2  = (const float*)d_in[10];
    const float* bo2  = (const float*)d_in[11];
    float* out = (float*)d_out;

    const int* seg = eidx + NATOMS;

    const size_t NF = (size_t)NATOMS * FDIM;   // 1,048,576

    float* q     = (float*)d_ws;               // qkv contiguous: q|k|v
    float* k     = q + NF;
    float* v     = k + NF;
    float* b_all = v + NF;                     // 768
    int*   off   = (int*)(b_all + 768);        // 129 ints, pad to 160
    unsigned short* xb = (unsigned short*)((float*)off + 160);  // NF bf16
    unsigned short* Wb = xb + NF;              // 768*256 bf16

    // 1. prep: bf16 conversions + bias concat + group offsets
    prep_kernel<<<1216, 256, 0, stream>>>(x, Wq, Wk, Wv, bq, bk, bv, seg,
                                          xb, Wb, b_all, off);

    // 2. fused QKV projection (bf16 MFMA)
    dim3 gproj(NATOMS / 64, 768 / 128);
    qkv_mfma<<<gproj, 256, 0, stream>>>(xb, Wb, b_all, q);

    // 3. attention row-sum + Wo1 + segment-count bias + Wo2 + silu, per group
    attn_out<<<NGRP, 256, 0, stream>>>(q, k, v, off, Wo1, bo1, Wo2, bo2, out);
}

// Round 3
// 131.311 us; speedup vs baseline: 1.0360x; 1.0360x over previous
//
#include <hip/hip_runtime.h>
#include <math.h>

#define NATOMS 4096
#define FDIM   256
#define NHEAD  8
#define DHEAD  32
#define NGRP   128

typedef __bf16 bf16x8 __attribute__((ext_vector_type(8)));
typedef float  floatx4 __attribute__((ext_vector_type(4)));

__device__ __forceinline__ float silu_f(float x) {
    return x / (1.0f + __expf(-x));
}

// Load 8 contiguous fp32 and convert to bf16x8 (RNE via native cast).
__device__ __forceinline__ bf16x8 cvt8(const float* __restrict__ p) {
    float4 lo = *(const float4*)p;
    float4 hi = *(const float4*)(p + 4);
    bf16x8 r;
    r[0] = (__bf16)lo.x; r[1] = (__bf16)lo.y; r[2] = (__bf16)lo.z; r[3] = (__bf16)lo.w;
    r[4] = (__bf16)hi.x; r[5] = (__bf16)hi.y; r[6] = (__bf16)hi.z; r[7] = (__bf16)hi.w;
    return r;
}

// ---------------------------------------------------------------------------
// Fused QKV projection: D[4096,768] = x @ [Wq|Wk|Wv]^T + bias, fp32 inputs
// converted to bf16 fragments in-register (no prep pass, no xb/Wb buffers).
// Block = 256 thr = 4 waves in 2x2; wave tile 32x64, block tile 64x128.
// Each by-block covers one half of one W (by>>1 selects Wq/Wk/Wv) -> uniform.
// Grid: (4096/64, 768/128) = (64, 6).
// First 129 blocks also each compute one group-offset binary search.
// ---------------------------------------------------------------------------
__global__ __launch_bounds__(256) void qkv_fused(
    const float* __restrict__ x,
    const float* __restrict__ Wq, const float* __restrict__ Wk, const float* __restrict__ Wv,
    const float* __restrict__ bq, const float* __restrict__ bk, const float* __restrict__ bv,
    const int* __restrict__ seg,
    float* __restrict__ qkv, int* __restrict__ off)
{
    int tid = threadIdx.x;

    // distributed group-offset computation: one search per block, thread 0
    int flat = blockIdx.y * gridDim.x + blockIdx.x;
    if (tid == 0 && flat <= NGRP) {
        int g = flat;
        if (g == NGRP) {
            off[NGRP] = NATOMS;
        } else {
            int lo = 0, hi = NATOMS;
            while (lo < hi) {
                int mid = (lo + hi) >> 1;
                if (seg[mid] < g) lo = mid + 1; else hi = mid;
            }
            off[g] = lo;
        }
    }

    int lane = tid & 63;
    int ww = tid >> 6;
    int wrow = ww >> 1, wcol = ww & 1;
    int m_base = blockIdx.x * 64 + wrow * 32;

    int w_idx  = blockIdx.y >> 1;                       // 0=Q 1=K 2=V (uniform)
    int c_base = (blockIdx.y & 1) * 128 + wcol * 64;    // row within W

    const float* W  = (w_idx == 0) ? Wq : (w_idx == 1) ? Wk : Wv;
    const float* bb = (w_idx == 0) ? bq : (w_idx == 1) ? bk : bv;

    int l15 = lane & 15;
    int quad = lane >> 4;
    int kq = quad * 8;

    floatx4 acc[2][4] = {};

    const float* ar0 = x + (size_t)(m_base + l15) * 256 + kq;
    const float* ar1 = ar0 + 16 * 256;
    const float* br[4];
#pragma unroll
    for (int ni = 0; ni < 4; ++ni)
        br[ni] = W + (size_t)(c_base + ni * 16 + l15) * 256 + kq;

#pragma unroll
    for (int ks = 0; ks < 8; ++ks) {
        int ko = ks * 32;
        bf16x8 a0 = cvt8(ar0 + ko);
        bf16x8 a1 = cvt8(ar1 + ko);
#pragma unroll
        for (int ni = 0; ni < 4; ++ni) {
            bf16x8 b = cvt8(br[ni] + ko);
            acc[0][ni] = __builtin_amdgcn_mfma_f32_16x16x32_bf16(a0, b, acc[0][ni], 0, 0, 0);
            acc[1][ni] = __builtin_amdgcn_mfma_f32_16x16x32_bf16(a1, b, acc[1][ni], 0, 0, 0);
        }
    }

#pragma unroll
    for (int mi = 0; mi < 2; ++mi) {
#pragma unroll
        for (int ni = 0; ni < 4; ++ni) {
            int c = c_base + ni * 16 + l15;
            float bias = bb[c];
            float* outp = qkv + (size_t)w_idx * (NATOMS * FDIM) + c;
#pragma unroll
            for (int r = 0; r < 4; ++r) {
                int row = m_base + mi * 16 + quad * 4 + r;
                outp[(size_t)row * FDIM] = acc[mi][ni][r] + bias;
            }
        }
    }
}

// ---------------------------------------------------------------------------
// Per (group g, head h): Ysum[g, h*32+d] = sum_j w_j * v_j[d],
//   w_j = sum_i silu(q_i . k_j)        (round-0 proven structure)
// Grid (128, 8), 256 thr: j = 32 lanes, i split 8 ways; q/v tiles in LDS.
// ---------------------------------------------------------------------------
#define JT 32
#define IT 64

__global__ __launch_bounds__(256) void attn_kernel(
    const float* __restrict__ q, const float* __restrict__ k,
    const float* __restrict__ v, const int* __restrict__ off,
    float* __restrict__ Ysum)
{
    int g = blockIdx.x, h = blockIdx.y;
    int base = off[g];
    int end  = off[g + 1];
    // clamp against garbage (rocprof replay may run with poisoned workspace)
    base = min(max(base, 0), NATOMS);
    end  = min(max(end, base), NATOMS);
    int n = end - base;

    __shared__ float4 qt4[IT * 8];
    __shared__ float4 vt4[JT * 8];
    __shared__ float  wred[8][JT];
    __shared__ float  w[JT];
    __shared__ float  red[8][DHEAD];

    int tid = threadIdx.x;
    int jj = tid & 31;
    int iq = tid >> 5;
    int d = tid & 31;
    int r = tid >> 5;

    const float4* q4 = (const float4*)(q + (size_t)base * FDIM) + h * 8;
    const float4* k4 = (const float4*)(k + (size_t)base * FDIM) + h * 8;
    const float4* v4 = (const float4*)(v + (size_t)base * FDIM) + h * 8;

    float accY = 0.0f;

    for (int j0 = 0; j0 < n; j0 += JT) {
        int jt_n = min(JT, n - j0);
        __syncthreads();
        for (int idx = tid; idx < jt_n * 8; idx += 256)
            vt4[idx] = v4[(size_t)(j0 + (idx >> 3)) * 64 + (idx & 7)];

        float4 kr[8];
        {
            int jrow = (jj < jt_n) ? (j0 + jj) : j0;
#pragma unroll
            for (int c = 0; c < 8; ++c) kr[c] = k4[(size_t)jrow * 64 + c];
        }

        float wpart = 0.0f;
        for (int i0 = 0; i0 < n; i0 += IT) {
            int it_n = min(IT, n - i0);
            __syncthreads();
            for (int idx = tid; idx < it_n * 8; idx += 256)
                qt4[idx] = q4[(size_t)(i0 + (idx >> 3)) * 64 + (idx & 7)];
            __syncthreads();
            if (jj < jt_n) {
                for (int ii = iq; ii < it_n; ii += 8) {
                    const float4* qr = &qt4[ii * 8];
                    float s = 0.0f;
#pragma unroll
                    for (int c = 0; c < 8; ++c) {
                        float4 a = qr[c];
                        s = fmaf(a.x, kr[c].x, s);
                        s = fmaf(a.y, kr[c].y, s);
                        s = fmaf(a.z, kr[c].z, s);
                        s = fmaf(a.w, kr[c].w, s);
                    }
                    wpart += silu_f(s);
                }
            }
        }
        wred[iq][jj] = wpart;
        __syncthreads();
        if (tid < JT) {
            float s = 0.0f;
#pragma unroll
            for (int rr = 0; rr < 8; ++rr) s += wred[rr][tid];
            w[tid] = s;
        }
        __syncthreads();
        const float* vts = (const float*)vt4;
        for (int j = r; j < jt_n; j += 8)
            accY = fmaf(w[j], vts[j * 32 + d], accY);
    }

    red[r][d] = accY;
    __syncthreads();
    if (r == 0) {
        float s = 0.0f;
#pragma unroll
        for (int rr = 0; rr < 8; ++rr) s += red[rr][d];
        Ysum[(size_t)g * FDIM + h * DHEAD + d] = s;
    }
}

// ---------------------------------------------------------------------------
// Per-group output: S = Ysum[g].Wo1^T + n*bo1 ; out = silu(S.Wo2^T + bo2).
// One block per group, one output column per thread. Wo rows are L2-hot
// (all 128 blocks read the same 2x256KB).
// ---------------------------------------------------------------------------
__global__ __launch_bounds__(256) void out_kernel(
    const float* __restrict__ Ysum, const int* __restrict__ off,
    const float* __restrict__ Wo1, const float* __restrict__ bo1,
    const float* __restrict__ Wo2, const float* __restrict__ bo2,
    float* __restrict__ out)
{
    int g = blockIdx.x;
    int tid = threadIdx.x;

    __shared__ float ybuf[FDIM];
    __shared__ float sbuf[FDIM];

    int base = off[g];
    int end  = off[g + 1];
    base = min(max(base, 0), NATOMS);
    end  = min(max(end, base), NATOMS);
    float cnt = (float)(end - base);

    ybuf[tid] = Ysum[(size_t)g * FDIM + tid];
    __syncthreads();

    const float4* y4 = (const float4*)ybuf;
    const float4* w1 = (const float4*)(Wo1 + (size_t)tid * FDIM);
    float acc = cnt * bo1[tid];
#pragma unroll
    for (int c = 0; c < 64; ++c) {
        float4 a = y4[c], b = w1[c];
        acc = fmaf(a.x, b.x, acc);
        acc = fmaf(a.y, b.y, acc);
        acc = fmaf(a.z, b.z, acc);
        acc = fmaf(a.w, b.w, acc);
    }
    sbuf[tid] = acc;
    __syncthreads();

    const float4* s4 = (const float4*)sbuf;
    const float4* w2 = (const float4*)(Wo2 + (size_t)tid * FDIM);
    float acc2 = bo2[tid];
#pragma unroll
    for (int c = 0; c < 64; ++c) {
        float4 a = s4[c], b = w2[c];
        acc2 = fmaf(a.x, b.x, acc2);
        acc2 = fmaf(a.y, b.y, acc2);
        acc2 = fmaf(a.z, b.z, acc2);
        acc2 = fmaf(a.w, b.w, acc2);
    }
    out[(size_t)g * FDIM + tid] = silu_f(acc2);
}

// ---------------------------------------------------------------------------
extern "C" void kernel_launch(void* const* d_in, const int* in_sizes, int n_in,
                              void* d_out, int out_size, void* d_ws, size_t ws_size,
                              hipStream_t stream) {
    const float* x    = (const float*)d_in[0];
    const int*   eidx = (const int*)  d_in[1];
    const float* Wq   = (const float*)d_in[2];
    const float* bq   = (const float*)d_in[3];
    const float* Wk   = (const float*)d_in[4];
    const float* bk   = (const float*)d_in[5];
    const float* Wv   = (const float*)d_in[6];
    const float* bv   = (const float*)d_in[7];
    const float* Wo1  = (const float*)d_in[8];
    const float* bo1  = (const float*)d_in[9];
    const float* Wo2  = (const float*)d_in[10];
    const float* bo2  = (const float*)d_in[11];
    float* out = (float*)d_out;

    const int* seg = eidx + NATOMS;

    const size_t NF = (size_t)NATOMS * FDIM;   // 1,048,576
    const size_t GF = (size_t)NGRP * FDIM;     // 32,768

    float* q    = (float*)d_ws;                // qkv contiguous: q|k|v
    float* k    = q + NF;
    float* v    = k + NF;
    float* Ysum = v + NF;
    int*   off  = (int*)(Ysum + GF);           // 129 ints

    // 1. fused QKV projection (inline fp32->bf16, MFMA) + group offsets
    dim3 gproj(NATOMS / 64, 768 / 128);
    qkv_fused<<<gproj, 256, 0, stream>>>(x, Wq, Wk, Wv, bq, bk, bv, seg, q, off);

    // 2. block-diagonal attention fused with per-group row-sum
    dim3 gattn(NGRP, NHEAD);
    attn_kernel<<<gattn, 256, 0, stream>>>(q, k, v, off, Ysum);

    // 3. per-group dual GEMV: Wo1 + count*bias, then Wo2 + silu
    out_kernel<<<NGRP, 256, 0, stream>>>(Ysum, off, Wo1, bo1, Wo2, bo2, out);
}